// Round 6
// baseline (494.105 us; speedup 1.0000x reference)
//
#include <hip/hip_runtime.h>

#define D 64
#define SH 8            // 256 cols per bucket
#define CPB 256         // 1<<SH
#define CH 4096         // edges per block in bucket kernels
#define MAXNB 512       // fast path supports N <= 131072 (also: src>>11 < 64)

// K1: per-block LDS histogram -> global bucket totals (atomic). Last-finisher
// block scans totals -> bbase + cursor init. (unchanged from R5, minus offsets)
__global__ __launch_bounds__(256) void count_scan(
    const int* __restrict__ es, int* __restrict__ btot,
    int* __restrict__ done, int* __restrict__ bbase,
    int* __restrict__ cursor, int NB, int E) {
  __shared__ int hist[MAXNB];
  __shared__ int sctmp[256];
  __shared__ int lastflag;
  int t = threadIdx.x;
  hist[t] = 0;
  hist[t + 256] = 0;
  __syncthreads();
  int base_e = blockIdx.x * CH;
#pragma unroll
  for (int j = 0; j < 16; j++) {
    int e = base_e + t + j * 256;
    if (e < E) atomicAdd(&hist[es[e] >> SH], 1);
  }
  __syncthreads();
  for (int b = t; b < NB; b += 256) {
    int h = hist[b];
    if (h) atomicAdd(&btot[b], h);
  }
  __syncthreads();
  if (t == 0) {
    __threadfence();
    int d = atomicAdd(done, 1);
    lastflag = (d == (int)gridDim.x - 1);
  }
  __syncthreads();
  if (!lastflag) return;
  __threadfence();
  int i0 = 2 * t, i1 = 2 * t + 1;
  int h0 = (i0 < NB) ? __hip_atomic_load(&btot[i0], __ATOMIC_RELAXED,
                                         __HIP_MEMORY_SCOPE_AGENT) : 0;
  int h1 = (i1 < NB) ? __hip_atomic_load(&btot[i1], __ATOMIC_RELAXED,
                                         __HIP_MEMORY_SCOPE_AGENT) : 0;
  int pair = h0 + h1;
  sctmp[t] = pair;
  __syncthreads();
  for (int off = 1; off < 256; off <<= 1) {
    int v = (t >= off) ? sctmp[t - off] : 0;
    __syncthreads();
    sctmp[t] += v;
    __syncthreads();
  }
  int excl = sctmp[t] - pair;
  if (i0 < NB) { bbase[i0] = excl; cursor[i0] = excl; }
  if (i1 < NB) { bbase[i1] = excl + h0; cursor[i1] = excl + h0; }
  if (t == 0) bbase[NB] = E;
}

// K2: re-histogram own chunk, reserve global range per bucket (one atomicAdd
// per block,bucket), LDS-stage by local rank, write coalesced runs to packed.
__global__ __launch_bounds__(256) void scatter_res(
    const int* __restrict__ es, int* __restrict__ cursor,
    int* __restrict__ packed, int NB, int E) {
  __shared__ int hist[MAXNB];
  __shared__ int lstart[MAXNB];
  __shared__ int gbase[MAXNB];
  __shared__ int lcur[MAXNB];
  __shared__ int sctmp[256];
  __shared__ int staged[CH];
  __shared__ unsigned short bidl[CH];
  int t = threadIdx.x;
  hist[t] = 0;
  hist[t + 256] = 0;
  __syncthreads();
  int base_e = blockIdx.x * CH;
  int c[16], r[16];
#pragma unroll
  for (int j = 0; j < 16; j++) {
    int e = base_e + t + j * 256;
    if (e < E) {
      c[j] = es[e];
      r[j] = es[E + e];
      atomicAdd(&hist[c[j] >> SH], 1);
    } else {
      c[j] = -1;
    }
  }
  __syncthreads();
  int h0 = hist[2 * t], h1 = hist[2 * t + 1];
  int pair = h0 + h1;
  sctmp[t] = pair;
  __syncthreads();
  for (int off = 1; off < 256; off <<= 1) {
    int v = (t >= off) ? sctmp[t - off] : 0;
    __syncthreads();
    sctmp[t] += v;
    __syncthreads();
  }
  int excl = sctmp[t] - pair;
  lstart[2 * t] = excl;
  lstart[2 * t + 1] = excl + h0;
  lcur[2 * t] = excl;
  lcur[2 * t + 1] = excl + h0;
  for (int b = t; b < NB; b += 256) {
    int h = hist[b];
    gbase[b] = h ? atomicAdd(&cursor[b], h) : 0;
  }
  __syncthreads();
#pragma unroll
  for (int j = 0; j < 16; j++) {
    if (c[j] >= 0) {
      int b = c[j] >> SH;
      int rank = atomicAdd(&lcur[b], 1);
      staged[rank] = (r[j] << SH) | (c[j] & (CPB - 1));
      bidl[rank] = (unsigned short)b;
    }
  }
  __syncthreads();
  int nloc = min(CH, E - base_e);
  for (int i = t; i < nloc; i += 256) {
    int b = bidl[i];
    packed[gbase[b] + (i - lstart[b])] = staged[i];
  }
}

// K3: per bucket, counting-sort by key = (local 16-node group, src>>11).
// Produces: spk (edges grouped per 16-node-group, src-ascending within group),
// cnts[node], goff[group] run starts. Within-key order arbitrary (fp32 sum
// reorder ~ULP, under tolerance).
__global__ __launch_bounds__(256) void sort_grp(
    const int* __restrict__ packed, const int* __restrict__ bbase,
    int* __restrict__ goff, int* __restrict__ cnts,
    int* __restrict__ spk, int N, int E, int NB) {
  __shared__ int kh[1024];
  __shared__ int kcur[1024];
  __shared__ int ncnt[256];
  __shared__ int sctmp[256];
  int b = blockIdx.x;
  int t = threadIdx.x;
  int s = bbase[b], e = bbase[b + 1];
  kh[t] = 0; kh[t + 256] = 0; kh[t + 512] = 0; kh[t + 768] = 0;
  ncnt[t] = 0;
  __syncthreads();
  for (int i = s + t; i < e; i += 256) {
    int p = packed[i];
    int d8 = p & 255;
    int key = ((d8 >> 4) << 6) | ((p >> 8) >> 11);
    atomicAdd(&kh[key], 1);
    atomicAdd(&ncnt[d8], 1);
  }
  __syncthreads();
  int k0 = kh[4 * t], k1 = kh[4 * t + 1], k2 = kh[4 * t + 2], k3 = kh[4 * t + 3];
  int sum = k0 + k1 + k2 + k3;
  sctmp[t] = sum;
  __syncthreads();
  for (int off = 1; off < 256; off <<= 1) {
    int v = (t >= off) ? sctmp[t - off] : 0;
    __syncthreads();
    sctmp[t] += v;
    __syncthreads();
  }
  int excl = sctmp[t] - sum;
  kcur[4 * t] = excl;
  kcur[4 * t + 1] = excl + k0;
  kcur[4 * t + 2] = excl + k0 + k1;
  kcur[4 * t + 3] = excl + k0 + k1 + k2;
  int node = (b << 8) + t;
  if (node < N) cnts[node] = ncnt[t];
  __syncthreads();
  if (t < 16) goff[b * 16 + t] = s + kcur[t * 64];
  if (b == NB - 1 && t == 0) goff[NB * 16] = E;
  __syncthreads();
  for (int i = s + t; i < e; i += 256) {
    int p = packed[i];
    int key = (((p & 255) >> 4) << 6) | ((p >> 8) >> 11);
    int rank = atomicAdd(&kcur[key], 1);
    spk[s + rank] = p;
  }
}

// K4: one wave per 16-node group; wave iterates its ~160 edges in ascending-
// source order (16 in flight) -> all waves sweep x together (L2/L3-resident
// window). LDS accumulator 16 nodes x 64 f32, stride 65 (bank-spread).
#define ASTR 65
__global__ __launch_bounds__(256) void node_reduce_grp(
    const float4* __restrict__ x4, const int* __restrict__ spk,
    const int* __restrict__ goff, const int* __restrict__ cnts,
    float* __restrict__ out, int N, int NG) {
  __shared__ float acc[4][16 * ASTR];
  int t = threadIdx.x;
  int w = t >> 6;
  int lane = t & 63;
  int g = blockIdx.x * 4 + w;
  if (g >= NG) return;
  float* aw = acc[w];
  for (int i = lane; i < 16 * ASTR; i += 64) aw[i] = 0.f;
  int s = goff[g], e = goff[g + 1];
  int eg = lane >> 4, d16 = lane & 15;
  for (int base = s; base < e; base += 16) {
    int i0 = base + eg, i1 = base + 4 + eg;
    int i2 = base + 8 + eg, i3 = base + 12 + eg;
    int p0 = (i0 < e) ? spk[i0] : -1;
    int p1 = (i1 < e) ? spk[i1] : -1;
    int p2 = (i2 < e) ? spk[i2] : -1;
    int p3 = (i3 < e) ? spk[i3] : -1;
    if (p0 >= 0) { float4 v = x4[(size_t)(p0 >> 8) * 16 + d16];
      float* a = &aw[(p0 & 15) * ASTR + d16 * 4];
      atomicAdd(a + 0, v.x); atomicAdd(a + 1, v.y);
      atomicAdd(a + 2, v.z); atomicAdd(a + 3, v.w); }
    if (p1 >= 0) { float4 v = x4[(size_t)(p1 >> 8) * 16 + d16];
      float* a = &aw[(p1 & 15) * ASTR + d16 * 4];
      atomicAdd(a + 0, v.x); atomicAdd(a + 1, v.y);
      atomicAdd(a + 2, v.z); atomicAdd(a + 3, v.w); }
    if (p2 >= 0) { float4 v = x4[(size_t)(p2 >> 8) * 16 + d16];
      float* a = &aw[(p2 & 15) * ASTR + d16 * 4];
      atomicAdd(a + 0, v.x); atomicAdd(a + 1, v.y);
      atomicAdd(a + 2, v.z); atomicAdd(a + 3, v.w); }
    if (p3 >= 0) { float4 v = x4[(size_t)(p3 >> 8) * 16 + d16];
      float* a = &aw[(p3 & 15) * ASTR + d16 * 4];
      atomicAdd(a + 0, v.x); atomicAdd(a + 1, v.y);
      atomicAdd(a + 2, v.z); atomicAdd(a + 3, v.w); }
  }
  // epilogue: two nodes at a time (sub = lane>>5); within sub-half:
  // lanes 0-15 write mean quarter, lanes 16-31 write x-copy quarter
  int sub = lane >> 5;
  int l5 = lane & 31;
  int h = l5 >> 4;
  int dd = l5 & 15;
  for (int n = 0; n < 16; n += 2) {
    int node = g * 16 + n + sub;
    if (node >= N) continue;
    int cn = cnts[node];
    float4* o4 = (float4*)(out + (size_t)node * 2 * D);
    if (h == 0) {
      float inv = 1.0f / (float)(cn > 0 ? cn : 1);
      float* a = &aw[(n + sub) * ASTR + dd * 4];
      o4[dd] = make_float4(a[0] * inv, a[1] * inv, a[2] * inv, a[3] * inv);
    } else {
      float4 v = (cn > 0) ? x4[(size_t)node * 16 + dd]
                          : make_float4(0.f, 0.f, 0.f, 0.f);
      o4[16 + dd] = v;
    }
  }
}

// ---------- fallback atomic path (only if fast path inapplicable) ----------

__global__ __launch_bounds__(256) void edge_scatter_atomic(
    const int* __restrict__ es, const float* __restrict__ x,
    float* __restrict__ out, int* __restrict__ count, int E) {
  int gid = blockIdx.x * blockDim.x + threadIdx.x;
  int e = gid >> 6;
  int lane = gid & 63;
  if (e >= E) return;
  int c = es[e];
  int r = es[E + e];
  if (lane == 0) atomicAdd(&count[c], 1);
  float v = x[(size_t)r * D + lane];
  unsafeAtomicAdd(&out[(size_t)c * 2 * D + lane], v);
}

__global__ __launch_bounds__(256) void finalize_atomic(
    const float* __restrict__ x, float* __restrict__ out,
    const int* __restrict__ count, int N) {
  int gid = blockIdx.x * blockDim.x + threadIdx.x;
  int node = gid >> 5;
  int j4 = gid & 31;
  if (node >= N) return;
  int cnt = count[node];
  float4* out4 = (float4*)(out + (size_t)node * 2 * D);
  if (j4 < 16) {
    float4 s = out4[j4];
    float inv = 1.0f / (float)(cnt > 0 ? cnt : 1);
    s.x *= inv; s.y *= inv; s.z *= inv; s.w *= inv;
    out4[j4] = s;
  } else {
    float4 v;
    if (cnt > 0) {
      const float4* x4 = (const float4*)(x + (size_t)node * D);
      v = x4[j4 - 16];
    } else {
      v = make_float4(0.f, 0.f, 0.f, 0.f);
    }
    out4[j4] = v;
  }
}

extern "C" void kernel_launch(void* const* d_in, const int* in_sizes, int n_in,
                              void* d_out, int out_size, void* d_ws, size_t ws_size,
                              hipStream_t stream) {
  const float* x = (const float*)d_in[0];
  const int* es = (const int*)d_in[1];
  int N = in_sizes[0] / D;
  int E = in_sizes[1] / 2;
  float* out = (float*)d_out;

  int NB = (N + CPB - 1) >> SH;
  int NBLK = (E + CH - 1) / CH;
  int NG = (N + 15) / 16;
  size_t need = ((size_t)NB + 1 + (NB + 1) + NB + (size_t)N +
                 ((size_t)NB * 16 + 1) + 2 * (size_t)E) * sizeof(int);
  if (NB > MAXNB || ws_size < need) {
    int* count = (int*)d_ws;
    hipMemsetAsync(count, 0, (size_t)N * sizeof(int), stream);
    hipMemsetAsync(out, 0, (size_t)N * 2 * D * sizeof(float), stream);
    long long t1 = (long long)E * 64;
    edge_scatter_atomic<<<(int)((t1 + 255) / 256), 256, 0, stream>>>(es, x, out, count, E);
    long long t2 = (long long)N * 32;
    finalize_atomic<<<(int)((t2 + 255) / 256), 256, 0, stream>>>(x, out, count, N);
    return;
  }

  int* ws = (int*)d_ws;
  int* btot = ws;                    // NB
  int* done = btot + NB;             // 1
  int* bbase = done + 1;             // NB+1
  int* cursor = bbase + NB + 1;      // NB
  int* cnts = cursor + NB;           // N
  int* goff = cnts + N;              // NB*16+1
  int* packed = goff + NB * 16 + 1;  // E
  int* spk = packed + E;             // E

  hipMemsetAsync(btot, 0, ((size_t)NB + 1) * sizeof(int), stream);

  count_scan<<<NBLK, 256, 0, stream>>>(es, btot, done, bbase, cursor, NB, E);
  scatter_res<<<NBLK, 256, 0, stream>>>(es, cursor, packed, NB, E);
  sort_grp<<<NB, 256, 0, stream>>>(packed, bbase, goff, cnts, spk, N, E, NB);
  node_reduce_grp<<<(NG + 3) / 4, 256, 0, stream>>>(
      (const float4*)x, spk, goff, cnts, out, N, NG);
}

// Round 7
// 160.965 us; speedup vs baseline: 3.0696x; 3.0696x over previous
//
#include <hip/hip_runtime.h>

#define D 64
#define SH 8            // 256 cols per bucket
#define CPB 256         // 1<<SH
#define CH 4096         // edges per block in bucket kernels
#define MAXNB 512       // fast path supports N <= 131072

// K1: per-block LDS histogram -> global bucket totals (atomic, ~391 adds/block
// on hot L2-resident counters). Last-finisher block (done-counter handshake,
// no dispatch-order assumption) scans totals -> bbase + cursor init.
__global__ __launch_bounds__(256) void count_scan(
    const int* __restrict__ es, int* __restrict__ btot,
    int* __restrict__ done, int* __restrict__ bbase,
    int* __restrict__ cursor, int* __restrict__ offsets,
    int NB, int E, int N) {
  __shared__ int hist[MAXNB];
  __shared__ int sctmp[256];
  __shared__ int lastflag;
  int t = threadIdx.x;
  hist[t] = 0;
  hist[t + 256] = 0;
  __syncthreads();
  int base_e = blockIdx.x * CH;
#pragma unroll
  for (int j = 0; j < 16; j++) {
    int e = base_e + t + j * 256;
    if (e < E) atomicAdd(&hist[es[e] >> SH], 1);
  }
  __syncthreads();
  for (int b = t; b < NB; b += 256) {
    int h = hist[b];
    if (h) atomicAdd(&btot[b], h);
  }
  __syncthreads();
  if (t == 0) {
    __threadfence();
    int d = atomicAdd(done, 1);
    lastflag = (d == (int)gridDim.x - 1);
  }
  __syncthreads();
  if (!lastflag) return;
  __threadfence();
  int i0 = 2 * t, i1 = 2 * t + 1;
  int h0 = (i0 < NB) ? __hip_atomic_load(&btot[i0], __ATOMIC_RELAXED,
                                         __HIP_MEMORY_SCOPE_AGENT) : 0;
  int h1 = (i1 < NB) ? __hip_atomic_load(&btot[i1], __ATOMIC_RELAXED,
                                         __HIP_MEMORY_SCOPE_AGENT) : 0;
  int pair = h0 + h1;
  sctmp[t] = pair;
  __syncthreads();
  for (int off = 1; off < 256; off <<= 1) {
    int v = (t >= off) ? sctmp[t - off] : 0;
    __syncthreads();
    sctmp[t] += v;
    __syncthreads();
  }
  int excl = sctmp[t] - pair;
  if (i0 < NB) { bbase[i0] = excl; cursor[i0] = excl; }
  if (i1 < NB) { bbase[i1] = excl + h0; cursor[i1] = excl + h0; }
  if (t == 0) { bbase[NB] = E; offsets[N] = E; }
}

// K2: re-histogram own chunk, reserve global range per bucket (one atomicAdd
// per block,bucket), LDS-stage by local rank, write coalesced runs to packed.
__global__ __launch_bounds__(256) void scatter_res(
    const int* __restrict__ es, int* __restrict__ cursor,
    int* __restrict__ packed, int NB, int E) {
  __shared__ int hist[MAXNB];
  __shared__ int lstart[MAXNB];
  __shared__ int gbase[MAXNB];
  __shared__ int lcur[MAXNB];
  __shared__ int sctmp[256];
  __shared__ int staged[CH];
  __shared__ unsigned short bidl[CH];
  int t = threadIdx.x;
  hist[t] = 0;
  hist[t + 256] = 0;
  __syncthreads();
  int base_e = blockIdx.x * CH;
  int c[16], r[16];
#pragma unroll
  for (int j = 0; j < 16; j++) {
    int e = base_e + t + j * 256;
    if (e < E) {
      c[j] = es[e];
      r[j] = es[E + e];
      atomicAdd(&hist[c[j] >> SH], 1);
    } else {
      c[j] = -1;
    }
  }
  __syncthreads();
  int h0 = hist[2 * t], h1 = hist[2 * t + 1];
  int pair = h0 + h1;
  sctmp[t] = pair;
  __syncthreads();
  for (int off = 1; off < 256; off <<= 1) {
    int v = (t >= off) ? sctmp[t - off] : 0;
    __syncthreads();
    sctmp[t] += v;
    __syncthreads();
  }
  int excl = sctmp[t] - pair;
  lstart[2 * t] = excl;
  lstart[2 * t + 1] = excl + h0;
  lcur[2 * t] = excl;
  lcur[2 * t + 1] = excl + h0;
  for (int b = t; b < NB; b += 256) {
    int h = hist[b];
    gbase[b] = h ? atomicAdd(&cursor[b], h) : 0;
  }
  __syncthreads();
#pragma unroll
  for (int j = 0; j < 16; j++) {
    if (c[j] >= 0) {
      int b = c[j] >> SH;
      int rank = atomicAdd(&lcur[b], 1);
      staged[rank] = (r[j] << SH) | (c[j] & (CPB - 1));
      bidl[rank] = (unsigned short)b;
    }
  }
  __syncthreads();
  int nloc = min(CH, E - base_e);
  for (int i = t; i < nloc; i += 256) {
    int b = bidl[i];
    packed[gbase[b] + (i - lstart[b])] = staged[i];
  }
}

// K3: one block per bucket: counting-sort run by exact column -> CSR
__global__ __launch_bounds__(256) void sort_cols(
    const int* __restrict__ packed, const int* __restrict__ bbase,
    int* __restrict__ offsets, int* __restrict__ sorted_rows, int N) {
  __shared__ int cnt[CPB];
  __shared__ int sctmp[256];
  __shared__ int cur[CPB];
  int b = blockIdx.x;
  int t = threadIdx.x;
  int s = bbase[b], e = bbase[b + 1];
  cnt[t] = 0;
  __syncthreads();
  for (int i = s + t; i < e; i += 256) atomicAdd(&cnt[packed[i] & (CPB - 1)], 1);
  __syncthreads();
  int v = cnt[t];
  sctmp[t] = v;
  __syncthreads();
  for (int off = 1; off < 256; off <<= 1) {
    int u = (t >= off) ? sctmp[t - off] : 0;
    __syncthreads();
    sctmp[t] += u;
    __syncthreads();
  }
  int excl = sctmp[t] - v;
  cur[t] = excl;
  int gc = (b << SH) + t;
  if (gc < N) offsets[gc] = s + excl;
  __syncthreads();
  for (int i = s + t; i < e; i += 256) {
    int p = packed[i];
    int rank = atomicAdd(&cur[p & (CPB - 1)], 1);
    sorted_rows[s + rank] = p >> SH;
  }
}

// K4: one wave per 4 consecutive nodes, software-pipelined: while gathering
// node n's rows, sorted_rows for node n+1 are already in flight. 4 lane-groups
// of 16, each owns one edge slot; lane reads one float4 of the 64-float row.
__global__ __launch_bounds__(256) void node_reduce4(
    const float4* __restrict__ x4, const int* __restrict__ sorted_rows,
    const int* __restrict__ offsets, float* __restrict__ out, int N) {
  int wid = (blockIdx.x * 256 + threadIdx.x) >> 6;
  int nb = wid * 4;
  if (nb >= N) return;
  int lane = threadIdx.x & 63;
  int eg = lane >> 4;
  int d16 = lane & 15;
  int l3 = lane & 3;
  int ia = nb + l3;       if (ia > N) ia = N;
  int ib = nb + l3 + 1;   if (ib > N) ib = N;
  int oa = offsets[ia];   // lane l3 holds start of node nb+l3
  int ob = offsets[ib];   // and its end
  // prefetch rows for node 0
  int s = __shfl(oa, 0), e = __shfl(ob, 0);
  int p0 = (s + eg < e)      ? sorted_rows[s + eg]      : -1;
  int p1 = (s + 4 + eg < e)  ? sorted_rows[s + 4 + eg]  : -1;
  int p2 = (s + 8 + eg < e)  ? sorted_rows[s + 8 + eg]  : -1;
  int p3 = (s + 12 + eg < e) ? sorted_rows[s + 12 + eg] : -1;
#pragma unroll
  for (int n = 0; n < 4; n++) {
    int node = nb + n;
    int cnt = e - s;
    int c0 = p0, c1 = p1, c2 = p2, c3 = p3;
    int sc = s;
    // prefetch next node's rows (in flight during this node's gather)
    if (n < 3) {
      s = __shfl(oa, n + 1); e = __shfl(ob, n + 1);
      p0 = (s + eg < e)      ? sorted_rows[s + eg]      : -1;
      p1 = (s + 4 + eg < e)  ? sorted_rows[s + 4 + eg]  : -1;
      p2 = (s + 8 + eg < e)  ? sorted_rows[s + 8 + eg]  : -1;
      p3 = (s + 12 + eg < e) ? sorted_rows[s + 12 + eg] : -1;
    }
    if (node >= N) continue;
    // copy-half source (eg==1 lanes only), issued alongside gathers
    float4 cpv = make_float4(0.f, 0.f, 0.f, 0.f);
    if (eg == 1) cpv = x4[(size_t)node * 16 + d16];
    float4 a0 = make_float4(0.f, 0.f, 0.f, 0.f);
    float4 a1 = make_float4(0.f, 0.f, 0.f, 0.f);
    float4 a2 = make_float4(0.f, 0.f, 0.f, 0.f);
    float4 a3 = make_float4(0.f, 0.f, 0.f, 0.f);
    if (c0 >= 0) { float4 v = x4[(size_t)c0 * 16 + d16];
      a0.x += v.x; a0.y += v.y; a0.z += v.z; a0.w += v.w; }
    if (c1 >= 0) { float4 v = x4[(size_t)c1 * 16 + d16];
      a1.x += v.x; a1.y += v.y; a1.z += v.z; a1.w += v.w; }
    if (c2 >= 0) { float4 v = x4[(size_t)c2 * 16 + d16];
      a2.x += v.x; a2.y += v.y; a2.z += v.z; a2.w += v.w; }
    if (c3 >= 0) { float4 v = x4[(size_t)c3 * 16 + d16];
      a3.x += v.x; a3.y += v.y; a3.z += v.z; a3.w += v.w; }
    // rare tail (cnt > 16): direct loads, wave-uniform branch
    for (int base = 16; base < cnt; base += 16) {
      int k0 = sc + base + eg;
      int k1 = sc + base + 4 + eg;
      int k2 = sc + base + 8 + eg;
      int k3 = sc + base + 12 + eg;
      int r0 = (k0 - sc < cnt) ? sorted_rows[k0] : -1;
      int r1 = (k1 - sc < cnt) ? sorted_rows[k1] : -1;
      int r2 = (k2 - sc < cnt) ? sorted_rows[k2] : -1;
      int r3 = (k3 - sc < cnt) ? sorted_rows[k3] : -1;
      if (r0 >= 0) { float4 v = x4[(size_t)r0 * 16 + d16];
        a0.x += v.x; a0.y += v.y; a0.z += v.z; a0.w += v.w; }
      if (r1 >= 0) { float4 v = x4[(size_t)r1 * 16 + d16];
        a1.x += v.x; a1.y += v.y; a1.z += v.z; a1.w += v.w; }
      if (r2 >= 0) { float4 v = x4[(size_t)r2 * 16 + d16];
        a2.x += v.x; a2.y += v.y; a2.z += v.z; a2.w += v.w; }
      if (r3 >= 0) { float4 v = x4[(size_t)r3 * 16 + d16];
        a3.x += v.x; a3.y += v.y; a3.z += v.z; a3.w += v.w; }
    }
    a0.x += a1.x + a2.x + a3.x;
    a0.y += a1.y + a2.y + a3.y;
    a0.z += a1.z + a2.z + a3.z;
    a0.w += a1.w + a2.w + a3.w;
    a0.x += __shfl_xor(a0.x, 16); a0.y += __shfl_xor(a0.y, 16);
    a0.z += __shfl_xor(a0.z, 16); a0.w += __shfl_xor(a0.w, 16);
    a0.x += __shfl_xor(a0.x, 32); a0.y += __shfl_xor(a0.y, 32);
    a0.z += __shfl_xor(a0.z, 32); a0.w += __shfl_xor(a0.w, 32);
    float4* o4 = (float4*)(out + (size_t)node * 2 * D);
    if (eg == 0) {
      float inv = 1.0f / (float)(cnt > 0 ? cnt : 1);
      a0.x *= inv; a0.y *= inv; a0.z *= inv; a0.w *= inv;
      o4[d16] = a0;
    } else if (eg == 1) {
      if (cnt <= 0) cpv = make_float4(0.f, 0.f, 0.f, 0.f);
      o4[16 + d16] = cpv;
    }
  }
}

// ---------- fallback atomic path (only if fast path inapplicable) ----------

__global__ __launch_bounds__(256) void edge_scatter_atomic(
    const int* __restrict__ es, const float* __restrict__ x,
    float* __restrict__ out, int* __restrict__ count, int E) {
  int gid = blockIdx.x * blockDim.x + threadIdx.x;
  int e = gid >> 6;
  int lane = gid & 63;
  if (e >= E) return;
  int c = es[e];
  int r = es[E + e];
  if (lane == 0) atomicAdd(&count[c], 1);
  float v = x[(size_t)r * D + lane];
  unsafeAtomicAdd(&out[(size_t)c * 2 * D + lane], v);
}

__global__ __launch_bounds__(256) void finalize_atomic(
    const float* __restrict__ x, float* __restrict__ out,
    const int* __restrict__ count, int N) {
  int gid = blockIdx.x * blockDim.x + threadIdx.x;
  int node = gid >> 5;
  int j4 = gid & 31;
  if (node >= N) return;
  int cnt = count[node];
  float4* out4 = (float4*)(out + (size_t)node * 2 * D);
  if (j4 < 16) {
    float4 s = out4[j4];
    float inv = 1.0f / (float)(cnt > 0 ? cnt : 1);
    s.x *= inv; s.y *= inv; s.z *= inv; s.w *= inv;
    out4[j4] = s;
  } else {
    float4 v;
    if (cnt > 0) {
      const float4* x4 = (const float4*)(x + (size_t)node * D);
      v = x4[j4 - 16];
    } else {
      v = make_float4(0.f, 0.f, 0.f, 0.f);
    }
    out4[j4] = v;
  }
}

extern "C" void kernel_launch(void* const* d_in, const int* in_sizes, int n_in,
                              void* d_out, int out_size, void* d_ws, size_t ws_size,
                              hipStream_t stream) {
  const float* x = (const float*)d_in[0];
  const int* es = (const int*)d_in[1];
  int N = in_sizes[0] / D;
  int E = in_sizes[1] / 2;
  float* out = (float*)d_out;

  int NB = (N + CPB - 1) >> SH;
  int NBLK = (E + CH - 1) / CH;
  size_t need = ((size_t)NB + 1 + (NB + 1) + NB + ((size_t)N + 1) +
                 2 * (size_t)E) * sizeof(int);
  if (NB > MAXNB || ws_size < need) {
    int* count = (int*)d_ws;
    hipMemsetAsync(count, 0, (size_t)N * sizeof(int), stream);
    hipMemsetAsync(out, 0, (size_t)N * 2 * D * sizeof(float), stream);
    long long t1 = (long long)E * 64;
    edge_scatter_atomic<<<(int)((t1 + 255) / 256), 256, 0, stream>>>(es, x, out, count, E);
    long long t2 = (long long)N * 32;
    finalize_atomic<<<(int)((t2 + 255) / 256), 256, 0, stream>>>(x, out, count, N);
    return;
  }

  int* ws = (int*)d_ws;
  int* btot = ws;                    // NB
  int* done = btot + NB;             // 1
  int* bbase = done + 1;             // NB+1
  int* cursor = bbase + NB + 1;      // NB
  int* offsets = cursor + NB;        // N+1
  int* packed = offsets + N + 1;     // E
  int* sorted_rows = packed + E;     // E

  hipMemsetAsync(btot, 0, ((size_t)NB + 1) * sizeof(int), stream);

  count_scan<<<NBLK, 256, 0, stream>>>(es, btot, done, bbase, cursor, offsets,
                                       NB, E, N);
  scatter_res<<<NBLK, 256, 0, stream>>>(es, cursor, packed, NB, E);
  sort_cols<<<NB, 256, 0, stream>>>(packed, bbase, offsets, sorted_rows, N);

  int waves = (N + 3) / 4;
  int blocks = (waves + 3) / 4;
  node_reduce4<<<blocks, 256, 0, stream>>>(
      (const float4*)x, sorted_rows, offsets, out, N);
}